// Round 2
// baseline (5322.673 us; speedup 1.0000x reference)
//
#include <hip/hip_runtime.h>
#include <hip/hip_cooperative_groups.h>
#include <math.h>

namespace cg = cooperative_groups;

#define Bq 16
#define Tq 32
#define Wq 128
#define Rq 4
#define Nq 512
#define Mq 128
#define DINq 768
#define XIPq 920
#define BTWq (Bq*Tq*Wq)
#define NBLK 144
#define NTHR 512

struct P {
  const float *X, *hs0, *mem0;
  const int *rst;
  const float *Wb,*bb,*Wff1,*bff1,*Wff2,*bff2,*Wta,*bta,*Wtb,*btb,*Wv,*bv,*Wr,*br,*Wxi,*bxi;
  float *out;
  float *memv,*link,*fwpart,*bw,*rw,*rca,*hs,*reads,*ww,*usage,*prec0,*prec1,*norms,*xi,*z;
  float *WbT,*Wff1T,*Wff2T,*WtaT,*WtbT,*WvT,*WrT,*WxiT;
};

__device__ __forceinline__ float dot4(float4 a, float4 b){
  return a.x*b.x + a.y*b.y + a.z*b.z + a.w*b.w;
}
__device__ __forceinline__ float sigf(float x){ return 1.f/(1.f+expf(-x)); }
__device__ __forceinline__ float oneplusf(float x){ return 1.f + log1pf(expf(x) + 1e-6f); }

__device__ __forceinline__ float wave_sum64(float v){
  #pragma unroll
  for (int m=32;m>=1;m>>=1) v += __shfl_xor(v, m, 64);
  return v;
}
__device__ __forceinline__ float wave_max64(float v){
  #pragma unroll
  for (int m=32;m>=1;m>>=1) v = fmaxf(v, __shfl_xor(v, m, 64));
  return v;
}
// block(512) reduces: shfl within wave + 8-slot LDS combine. 2 syncs each.
__device__ __forceinline__ float blk_sum(float v, float* s8){
  int w = threadIdx.x>>6;
  v = wave_sum64(v);
  if ((threadIdx.x&63)==0) s8[w] = v;
  __syncthreads();
  float r = s8[0]+s8[1]+s8[2]+s8[3]+s8[4]+s8[5]+s8[6]+s8[7];
  __syncthreads();
  return r;
}
__device__ __forceinline__ float blk_max(float v, float* s8){
  int w = threadIdx.x>>6;
  v = wave_max64(v);
  if ((threadIdx.x&63)==0) s8[w] = v;
  __syncthreads();
  float r = s8[0];
  #pragma unroll
  for (int q=1;q<8;q++) r = fmaxf(r, s8[q]);
  __syncthreads();
  return r;
}

// ---------------- init: copy state, zero buffers, transpose weights ----------------
__global__ __launch_bounds__(256) void k_init(P p){
  int bid = blockIdx.x, tid = threadIdx.x;
  if (bid < 32){
    int gid = bid*256 + tid;
    const float4* src = (const float4*)(p.mem0 + (size_t)gid*Mq);
    float4* dst = (float4*)(p.memv + (size_t)gid*Mq);
    float s = 0.f;
    #pragma unroll 8
    for (int c=0;c<32;c++){ float4 v = src[c]; dst[c]=v; s += dot4(v,v); }
    p.norms[gid] = sqrtf(s);
  } else if (bid < 224){
    float4* L = (float4*)p.link;
    int idx = (bid-32)*256 + tid; int stride = 192*256;
    float4 z4 = make_float4(0.f,0.f,0.f,0.f);
    for (int i=idx; i<(Bq*Nq*Nq)/4; i+=stride) L[i] = z4;
  } else if (bid == 224){
    for (int i=tid;i<Bq*Nq;i+=256){ p.usage[i]=0.f; p.prec0[i]=0.f; p.prec1[i]=0.f; p.ww[i]=0.f; }
    for (int i=tid;i<Bq*Rq*Nq;i+=256) p.rw[i]=0.f;
    for (int i=tid;i<Bq*Rq*Wq;i+=256) p.reads[i]=0.f;
    for (int i=tid;i<Bq*Wq;i+=256) p.hs[i]=p.hs0[i];
  } else if (bid < 233){            // WbT: (768,128) -> (128,768)
    int idx=(bid-225)*256+tid, stride=8*256;
    for (int k=idx;k<DINq*Wq;k+=stride){ int j=k/DINq, i=k%DINq; p.WbT[k]=p.Wb[i*Wq+j]; }
  } else if (bid < 235){
    int idx=(bid-233)*256+tid, stride=2*256;
    for (int k=idx;k<Wq*Wq;k+=stride){ int j=k/Wq, i=k%Wq; p.Wff1T[k]=p.Wff1[i*Wq+j]; }
  } else if (bid < 237){
    int idx=(bid-235)*256+tid, stride=2*256;
    for (int k=idx;k<Wq*Wq;k+=stride){ int j=k/Wq, i=k%Wq; p.Wff2T[k]=p.Wff2[i*Wq+j]; }
  } else if (bid < 239){
    int idx=(bid-237)*256+tid, stride=2*256;
    for (int k=idx;k<Wq*Wq;k+=stride){ int j=k/Wq, i=k%Wq; p.WtaT[k]=p.Wta[i*Wq+j]; }
  } else if (bid < 241){
    int idx=(bid-239)*256+tid, stride=2*256;
    for (int k=idx;k<Wq*Wq;k+=stride){ int j=k/Wq, i=k%Wq; p.WtbT[k]=p.Wtb[i*Wq+j]; }
  } else if (bid < 243){
    int idx=(bid-241)*256+tid, stride=2*256;
    for (int k=idx;k<Wq*Wq;k+=stride){ int j=k/Wq, i=k%Wq; p.WvT[k]=p.Wv[i*Wq+j]; }
  } else if (bid < 247){            // WrT: (512,128) -> (128,512)
    int idx=(bid-243)*256+tid, stride=4*256;
    for (int k=idx;k<Rq*Wq*Wq;k+=stride){ int j=k/(Rq*Wq), i=k%(Rq*Wq); p.WrT[k]=p.Wr[i*Wq+j]; }
  } else if (bid < 255){            // WxiT: (128,919) -> (919,128)
    int idx=(bid-247)*256+tid, stride=8*256;
    for (int k=idx;k<919*Wq;k+=stride){ int f=k/Wq, i=k%Wq; p.WxiT[k]=p.Wxi[i*919+f]; }
  }
}

union __align__(16) SMem {
  struct { float hsall[Bq*Wq]; } xi;                                   // 8 KB
  struct { float hsb[Wq]; float key[Wq]; float wcas[Nq]; float uarr[Nq];
           float cp[Nq]; float s8[8]; int sidx[Nq]; } addr;            // ~9.3 KB
  struct { float fwacc[Rq*Nq]; } link;                                 // 8 KB
  struct { float key[Rq*Wq]; float wv[Wq]; float er[Wq]; float s8[8]; } memb;
  struct { float rwl[Rq*Nq]; } rd;                                     // 8 KB
};

__global__ __launch_bounds__(NTHR) void k_dnc(P p){
  cg::grid_group grid = cg::this_grid();
  const int bid = blockIdx.x, tid = threadIdx.x;
  __shared__ SMem sm;

  for (int t=0; t<Tq; t++){
    // ======== P1: z(t) (+ y(t-1)), blocks 0..127 = output index j ========
    if (bid < 128){
      int j = bid;
      int b = tid>>5, l = tid&31;
      float keep = 1.f - (float)p.rst[b*Tq + t];
      const float4* w4 = (const float4*)(p.WbT + (size_t)j*DINq);
      const float4* x4 = (const float4*)(p.X + ((size_t)(b*Tq+t))*Wq);
      const float4* r4 = (const float4*)(p.reads + (size_t)b*Rq*Wq);
      const float4* h4 = (const float4*)(p.hs + (size_t)b*Wq);
      float acc = 0.f;
      #pragma unroll
      for (int q=0;q<6;q++){
        int c = l*6+q;
        float4 iv;
        if (c < 32) iv = x4[c];
        else if (c < 160) iv = r4[c-32];
        else { iv = h4[c-160]; iv.x*=keep; iv.y*=keep; iv.z*=keep; iv.w*=keep; }
        acc += dot4(w4[c], iv);
      }
      #pragma unroll
      for (int m=16;m>=1;m>>=1) acc += __shfl_xor(acc, m, 32);
      if (l==0){
        float a = acc + p.bb[j];
        p.z[b*Wq + j] = a * sigf(a);
      }
      if (t > 0){
        const float4* wv4 = (const float4*)(p.WvT + (size_t)j*Wq);
        const float4* wr4 = (const float4*)(p.WrT + (size_t)j*(Rq*Wq));
        float ya = dot4(wv4[l], h4[l]);
        #pragma unroll
        for (int q=0;q<4;q++){ int c = l*4+q; ya += dot4(wr4[c], r4[c]); }
        #pragma unroll
        for (int m=16;m>=1;m>>=1) ya += __shfl_xor(ya, m, 32);
        if (l==0) p.out[((size_t)b*Tq + (t-1))*Wq + j] = ya + p.bv[j] + p.br[j];
      }
    }
    grid.sync();

    // ======== P2: hs(t), blocks 0..127 = j ========
    if (bid < 128){
      int j = bid; int b = tid>>5, l = tid&31;
      float4 zv = ((const float4*)(p.z + b*Wq))[l];
      float a1 = dot4(((const float4*)(p.Wff1T + j*Wq))[l], zv);
      float a2 = dot4(((const float4*)(p.Wff2T + j*Wq))[l], zv);
      float aa = dot4(((const float4*)(p.WtaT  + j*Wq))[l], zv);
      float ab = dot4(((const float4*)(p.WtbT  + j*Wq))[l], zv);
      #pragma unroll
      for (int m=16;m>=1;m>>=1){
        a1 += __shfl_xor(a1, m, 32); a2 += __shfl_xor(a2, m, 32);
        aa += __shfl_xor(aa, m, 32); ab += __shfl_xor(ab, m, 32);
      }
      if (l==0){
        a1 += p.bff1[j]; a2 += p.bff2[j]; aa += p.bta[j]; ab += p.btb[j];
        float ti = sigf(aa*(float)t + ab);
        float h = a1*(1.f-ti) + ti*a2;
        p.hs[b*Wq+j] = h;
        p.out[BTWq + ((size_t)b*Tq + t)*Wq + j] = h;
      }
    }
    grid.sync();

    // ======== P3: addr (blocks 0..15, per batch) || xi features (16..143) ========
    if (bid >= 16){
      // xi features: read keys 0..511, write_vec 640..767, erase 768..895
      int fb = bid - 16;                    // 0..127, 6 features each
      ((float4*)sm.xi.hsall)[tid] = ((const float4*)p.hs)[tid];
      __syncthreads();
      if (tid < 96){
        int q = tid>>4, b = tid&15;
        int idx = fb*6 + q;
        int f = (idx<512)? idx : idx+128;
        const float4* wx = (const float4*)(p.WxiT + (size_t)f*Wq);
        const float4* hh = ((const float4*)sm.xi.hsall) + b*32;
        float acc = p.bxi[f];
        #pragma unroll 8
        for (int c=0;c<32;c++) acc += dot4(wx[c], hh[c]);
        p.xi[b*XIPq + f] = acc;
      }
    } else {
      int b = bid;
      float* hsb = sm.addr.hsb;
      float* key = sm.addr.key;
      if (tid < 32) ((float4*)hsb)[tid] = ((const float4*)(p.hs + b*Wq))[tid];
      __syncthreads();
      const float* xib = p.xi + b*XIPq;
      if (tid < 151){                      // write_key 512..639 + scalars 896..918
        int f = (tid<128)? (512+tid) : (896 + (tid-128));
        const float4* wx = (const float4*)(p.WxiT + (size_t)f*Wq);
        const float4* hh = (const float4*)hsb;
        float acc = p.bxi[f];
        #pragma unroll 8
        for (int c=0;c<32;c++) acc += dot4(wx[c], hh[c]);
        p.xi[b*XIPq + f] = acc;
        if (tid < 128) key[tid] = acc;
      }
      __syncthreads();
      float kk = (tid<128)? key[tid]*key[tid] : 0.f;
      float kn = sqrtf(blk_sum(kk, sm.addr.s8));
      float keep = 1.f - (float)p.rst[b*Tq + t];
      int n = tid;
      const float4* k4 = (const float4*)key;
      const float4* mrow = (const float4*)(p.memv + ((size_t)b*Nq+n)*Mq);
      float d = 0.f;
      #pragma unroll 8
      for (int c=0;c<32;c++) d += dot4(k4[c], mrow[c]);
      float mn = p.norms[b*Nq + n];
      float sim = (keep*d) / (kn*(keep*mn) + 1e-6f);
      float wstr = oneplusf(xib[916]);
      float v = wstr*sim;
      float mx = blk_max(v, sm.addr.s8);
      float e = expf(v - mx);
      float se = blk_sum(e, sm.addr.s8);
      sm.addr.wcas[n] = e/se;
      // usage update (prev rw, prev ww still in globals)
      float ret = 1.f;
      #pragma unroll
      for (int rr=0;rr<Rq;rr++){
        float fg = sigf(xib[896+rr]);
        ret *= 1.f - fg * p.rw[((size_t)b*Rq+rr)*Nq + n];
      }
      float uo = p.usage[b*Nq+n], pw = p.ww[b*Nq+n];
      float u = (uo + pw - uo*pw)*ret;
      p.usage[b*Nq+n] = u;
      sm.addr.uarr[n] = u;
      __syncthreads();
      // stable ascending rank: #{j: u_j<u_i} + #{j<i: u_j==u_i}
      int rank = 0;
      const float4* u4 = (const float4*)sm.addr.uarr;
      for (int jj=0; jj<128; jj++){
        float4 vv = u4[jj]; int j0 = jj*4;
        rank += (vv.x<u) || (vv.x==u && (j0+0)<n);
        rank += (vv.y<u) || (vv.y==u && (j0+1)<n);
        rank += (vv.z<u) || (vv.z==u && (j0+2)<n);
        rank += (vv.w<u) || (vv.w==u && (j0+3)<n);
      }
      sm.addr.sidx[rank] = n;
      __syncthreads();
      int si = sm.addr.sidx[n];            // orig index of rank-n element
      float sv = sm.addr.uarr[si];         // sorted value at rank n
      // inclusive cumprod over rank order: shfl scan within wave + wave offsets
      int w = tid>>6, l = tid&63;
      float x = sv;
      #pragma unroll
      for (int dd=1; dd<64; dd<<=1){
        float pr = __shfl_up(x, dd, 64);
        if (l >= dd) x *= pr;
      }
      if (l==63) sm.addr.s8[w] = x;
      __syncthreads();
      float woff = 1.f;
      #pragma unroll
      for (int q=0;q<8;q++) if (q < w) woff *= sm.addr.s8[q];
      x *= woff;
      sm.addr.cp[n] = x;
      __syncthreads();
      float alloc = (1.f - u) * sm.addr.cp[si];   // reference's cp[si[k]] indexing
      float ag = sigf(xib[917]), wg = sigf(xib[918]);
      float wwv = wg*(ag*alloc + (1.f-ag)*sm.addr.wcas[n]);
      p.ww[b*Nq+n] = wwv;
      float wsum = blk_sum(wwv, sm.addr.s8);
      const float* po = (t&1)? p.prec1 : p.prec0;
      float*       pn = (t&1)? p.prec0 : p.prec1;
      pn[b*Nq+n] = (1.f - wsum)*po[b*Nq+n] + wwv;
    }
    grid.sync();

    // ======== P4: link+fw/bw (0..127) || mem update + rca (128..143) ========
    {
      const float* po = (t&1)? p.prec1 : p.prec0;
      if (bid < 128){
        int b = bid>>3, g = bid&7;           // 64 rows per block
        #pragma unroll
        for (int i=0;i<4;i++) sm.link.fwacc[i*512+tid] = 0.f;
        __syncthreads();
        int w = tid>>6, l = tid&63, c0 = l*8;
        const float* wwb = p.ww + b*Nq;
        const float* pob = po + b*Nq;
        float ww8[8], pc8[8], pr8[Rq][8];
        *(float4*)&ww8[0] = *(const float4*)(wwb + c0);
        *(float4*)&ww8[4] = *(const float4*)(wwb + c0 + 4);
        *(float4*)&pc8[0] = *(const float4*)(pob + c0);
        *(float4*)&pc8[4] = *(const float4*)(pob + c0 + 4);
        #pragma unroll
        for (int r=0;r<Rq;r++){
          *(float4*)&pr8[r][0] = *(const float4*)(p.rw + ((size_t)b*Rq+r)*Nq + c0);
          *(float4*)&pr8[r][4] = *(const float4*)(p.rw + ((size_t)b*Rq+r)*Nq + c0 + 4);
        }
        float fa[Rq][8];
        #pragma unroll
        for (int r=0;r<Rq;r++)
          #pragma unroll
          for (int q=0;q<8;q++) fa[r][q]=0.f;
        for (int rr=0; rr<8; rr++){
          int n = g*64 + w*8 + rr;
          float wwn = wwb[n];
          float prn[Rq];
          #pragma unroll
          for (int r=0;r<Rq;r++) prn[r] = p.rw[((size_t)b*Rq+r)*Nq + n];
          size_t row = ((size_t)b*Nq + n)*Nq;
          float4 La = *(const float4*)(p.link + row + c0);
          float4 Lb = *(const float4*)(p.link + row + c0 + 4);
          float vv[8] = {La.x,La.y,La.z,La.w,Lb.x,Lb.y,Lb.z,Lb.w};
          float bwp[Rq] = {0.f,0.f,0.f,0.f};
          #pragma unroll
          for (int q=0;q<8;q++){
            float nv = (1.f - wwn - ww8[q])*vv[q] + wwn*pc8[q];
            if (c0 + q == n) nv = 0.f;
            vv[q] = nv;
            #pragma unroll
            for (int r=0;r<Rq;r++){ fa[r][q] += prn[r]*nv; bwp[r] += pr8[r][q]*nv; }
          }
          *(float4*)(p.link + row + c0)     = make_float4(vv[0],vv[1],vv[2],vv[3]);
          *(float4*)(p.link + row + c0 + 4) = make_float4(vv[4],vv[5],vv[6],vv[7]);
          #pragma unroll
          for (int m=1;m<64;m<<=1)
            #pragma unroll
            for (int r=0;r<Rq;r++) bwp[r] += __shfl_xor(bwp[r], m, 64);
          if (l==0){
            #pragma unroll
            for (int r=0;r<Rq;r++) p.bw[((size_t)b*Rq+r)*Nq + n] = bwp[r];
          }
        }
        #pragma unroll
        for (int r=0;r<Rq;r++)
          #pragma unroll
          for (int q=0;q<8;q++) atomicAdd(&sm.link.fwacc[r*Nq + c0 + q], fa[r][q]);
        __syncthreads();
        #pragma unroll
        for (int i=0;i<4;i++){
          int id = i*512 + tid; int r = id>>9, k = id&511;
          p.fwpart[(((size_t)(b*8+g))*Rq + r)*Nq + k] = sm.link.fwacc[id];
        }
      } else {
        int b = bid - 128;
        const float* xib = p.xi + b*XIPq;
        sm.memb.key[tid] = xib[tid];          // raw read keys 0..511
        if (tid < 128){ sm.memb.wv[tid] = xib[640+tid]; sm.memb.er[tid] = sigf(xib[768+tid]); }
        __syncthreads();
        float kn4[4], rstr[4];
        #pragma unroll
        for (int r=0;r<Rq;r++){
          float kk = (tid<128)? sm.memb.key[r*128+tid]*sm.memb.key[r*128+tid] : 0.f;
          kn4[r] = sqrtf(blk_sum(kk, sm.memb.s8));
          rstr[r] = oneplusf(xib[900+r]);
        }
        int n = tid;
        float keep = 1.f - (float)p.rst[b*Tq + t];
        float wwn = p.ww[b*Nq+n];
        float4* mrow = (float4*)(p.memv + ((size_t)b*Nq+n)*Mq);
        const float4* er4 = (const float4*)sm.memb.er;
        const float4* wv4 = (const float4*)sm.memb.wv;
        const float4* k40 = (const float4*)(sm.memb.key);
        const float4* k41 = (const float4*)(sm.memb.key+128);
        const float4* k42 = (const float4*)(sm.memb.key+256);
        const float4* k43 = (const float4*)(sm.memb.key+384);
        float s = 0.f, d0=0.f, d1=0.f, d2=0.f, d3=0.f;
        #pragma unroll 4
        for (int c=0;c<32;c++){
          float4 mv = mrow[c], e4 = er4[c], w4 = wv4[c];
          mv.x = mv.x*keep*(1.f - wwn*e4.x) + wwn*w4.x;
          mv.y = mv.y*keep*(1.f - wwn*e4.y) + wwn*w4.y;
          mv.z = mv.z*keep*(1.f - wwn*e4.z) + wwn*w4.z;
          mv.w = mv.w*keep*(1.f - wwn*e4.w) + wwn*w4.w;
          s += dot4(mv,mv);
          d0 += dot4(k40[c], mv); d1 += dot4(k41[c], mv);
          d2 += dot4(k42[c], mv); d3 += dot4(k43[c], mv);
          mrow[c] = mv;
        }
        float mn = sqrtf(s);
        p.norms[b*Nq+n] = mn;
        float dd[4] = {d0,d1,d2,d3};
        #pragma unroll
        for (int r=0;r<Rq;r++){
          float v = rstr[r] * (dd[r] / (kn4[r]*mn + 1e-6f));
          float mx = blk_max(v, sm.memb.s8);
          float e = expf(v - mx);
          float se = blk_sum(e, sm.memb.s8);
          p.rca[((size_t)(b*Rq+r))*Nq + n] = e/se;
        }
      }
    }
    grid.sync();

    // ======== P5: rw combine + reads, blocks 0..15 ========
    if (bid < 16){
      int b = bid;
      const float* xib = p.xi + b*XIPq;
      #pragma unroll
      for (int r=0;r<Rq;r++){
        float m0 = xib[904+r*3], m1 = xib[905+r*3], m2 = xib[906+r*3];
        float mm = fmaxf(m0, fmaxf(m1,m2));
        float e0 = expf(m0-mm), e1 = expf(m1-mm), e2 = expf(m2-mm);
        float es = e0+e1+e2;
        int k = tid;
        float fwv = 0.f;
        #pragma unroll
        for (int g=0; g<8; g++) fwv += p.fwpart[(((size_t)(b*8+g))*Rq + r)*Nq + k];
        float bwv  = p.bw[((size_t)b*Rq+r)*Nq + k];
        float rcav = p.rca[((size_t)(b*Rq+r))*Nq + k];
        float rwv = (e0*bwv + e1*rcav + e2*fwv)/es;
        sm.rd.rwl[r*Nq + k] = rwv;
        p.rw[((size_t)b*Rq+r)*Nq + k] = rwv;
      }
      __syncthreads();
      int r = tid>>7, m = tid&127;
      const float* rl = sm.rd.rwl + r*Nq;
      const float* mb = p.memv + (size_t)b*Nq*Mq + m;
      float acc = 0.f;
      #pragma unroll 8
      for (int n=0;n<Nq;n++) acc += rl[n]*mb[(size_t)n*Mq];
      p.reads[b*Rq*Wq + tid] = acc;
    }
    grid.sync();
  } // t loop

  // ======== epilogue: y(T-1) ========
  if (bid < 128){
    int j = bid; int b = tid>>5, l = tid&31;
    const float4* h4 = (const float4*)(p.hs + (size_t)b*Wq);
    const float4* r4 = (const float4*)(p.reads + (size_t)b*Rq*Wq);
    const float4* wv4 = (const float4*)(p.WvT + (size_t)j*Wq);
    const float4* wr4 = (const float4*)(p.WrT + (size_t)j*(Rq*Wq));
    float ya = dot4(wv4[l], h4[l]);
    #pragma unroll
    for (int q=0;q<4;q++){ int c = l*4+q; ya += dot4(wr4[c], r4[c]); }
    #pragma unroll
    for (int m=16;m>=1;m>>=1) ya += __shfl_xor(ya, m, 32);
    if (l==0) p.out[((size_t)b*Tq + (Tq-1))*Wq + j] = ya + p.bv[j] + p.br[j];
  }
}

extern "C" void kernel_launch(void* const* d_in, const int* in_sizes, int n_in,
                              void* d_out, int out_size, void* d_ws, size_t ws_size,
                              hipStream_t stream){
  (void)in_sizes; (void)n_in; (void)out_size; (void)ws_size;
  P p;
  p.X    = (const float*)d_in[0];
  p.hs0  = (const float*)d_in[1];
  p.mem0 = (const float*)d_in[2];
  p.rst  = (const int*)d_in[3];
  p.Wb   = (const float*)d_in[4];  p.bb   = (const float*)d_in[5];
  p.Wff1 = (const float*)d_in[6];  p.bff1 = (const float*)d_in[7];
  p.Wff2 = (const float*)d_in[8];  p.bff2 = (const float*)d_in[9];
  p.Wta  = (const float*)d_in[10]; p.bta  = (const float*)d_in[11];
  p.Wtb  = (const float*)d_in[12]; p.btb  = (const float*)d_in[13];
  p.Wv   = (const float*)d_in[14]; p.bv   = (const float*)d_in[15];
  p.Wr   = (const float*)d_in[16]; p.br   = (const float*)d_in[17];
  p.Wxi  = (const float*)d_in[18]; p.bxi  = (const float*)d_in[19];
  p.out = (float*)d_out;
  float* ws = (float*)d_ws;
  size_t o = 0;
  p.memv   = ws + o; o += (size_t)Bq*Nq*Mq;       // 1,048,576
  p.link   = ws + o; o += (size_t)Bq*Nq*Nq;       // 4,194,304
  p.fwpart = ws + o; o += (size_t)Bq*8*Rq*Nq;     //   262,144
  p.bw     = ws + o; o += (size_t)Bq*Rq*Nq;
  p.rw     = ws + o; o += (size_t)Bq*Rq*Nq;
  p.rca    = ws + o; o += (size_t)Bq*Rq*Nq;
  p.hs     = ws + o; o += (size_t)Bq*Wq;
  p.reads  = ws + o; o += (size_t)Bq*Rq*Wq;
  p.ww     = ws + o; o += (size_t)Bq*Nq;
  p.usage  = ws + o; o += (size_t)Bq*Nq;
  p.prec0  = ws + o; o += (size_t)Bq*Nq;
  p.prec1  = ws + o; o += (size_t)Bq*Nq;
  p.norms  = ws + o; o += (size_t)Bq*Nq;
  p.xi     = ws + o; o += (size_t)Bq*XIPq;
  p.z      = ws + o; o += (size_t)Bq*Wq;
  p.WbT    = ws + o; o += (size_t)DINq*Wq;
  p.Wff1T  = ws + o; o += (size_t)Wq*Wq;
  p.Wff2T  = ws + o; o += (size_t)Wq*Wq;
  p.WtaT   = ws + o; o += (size_t)Wq*Wq;
  p.WtbT   = ws + o; o += (size_t)Wq*Wq;
  p.WvT    = ws + o; o += (size_t)Wq*Wq;
  p.WrT    = ws + o; o += (size_t)Rq*Wq*Wq;
  p.WxiT   = ws + o; o += (size_t)919*Wq;

  hipLaunchKernelGGL(k_init, dim3(320), dim3(256), 0, stream, p);
  void* args[] = { (void*)&p };
  hipLaunchCooperativeKernel((void*)k_dnc, dim3(NBLK), dim3(NTHR), args, 0, stream);
}

// Round 3
// 3661.050 us; speedup vs baseline: 1.4539x; 1.4539x over previous
//
#include <hip/hip_runtime.h>
#include <math.h>

#define Bq 16
#define Tq 32
#define Wq 128
#define Rq 4
#define Nq 512
#define Mq 128
#define DINq 768
#define XIPq 920
#define BTWq (Bq*Tq*Wq)

struct P {
  const float *X, *hs0, *mem0;
  const int *rst;
  const float *Wb,*bb,*Wff1,*bff1,*Wff2,*bff2,*Wta,*bta,*Wtb,*btb,*Wv,*bv,*Wr,*br,*Wxi,*bxi;
  float *out;
  float *memv,*link,*fwpart,*bw,*rw,*rca,*hs,*ww,*usage,*prec0,*prec1,*norms,*xi;
  float *WbT,*Wff1T,*Wff2T,*WtaT,*WtbT,*WvT,*WrT,*WxiT;
};

__device__ __forceinline__ float dot4(float4 a, float4 b){
  return a.x*b.x + a.y*b.y + a.z*b.z + a.w*b.w;
}
__device__ __forceinline__ float sigf(float x){ return 1.f/(1.f+expf(-x)); }
__device__ __forceinline__ float oneplusf(float x){ return 1.f + log1pf(expf(x) + 1e-6f); }

__device__ __forceinline__ float wave_sum64(float v){
  #pragma unroll
  for (int m=32;m>=1;m>>=1) v += __shfl_xor(v, m, 64);
  return v;
}
__device__ __forceinline__ float wave_max64(float v){
  #pragma unroll
  for (int m=32;m>=1;m>>=1) v = fmaxf(v, __shfl_xor(v, m, 64));
  return v;
}
__device__ __forceinline__ float blk_sum(float v, float* s8){
  int w = threadIdx.x>>6;
  v = wave_sum64(v);
  if ((threadIdx.x&63)==0) s8[w] = v;
  __syncthreads();
  float r = s8[0]+s8[1]+s8[2]+s8[3]+s8[4]+s8[5]+s8[6]+s8[7];
  __syncthreads();
  return r;
}
__device__ __forceinline__ float blk_max(float v, float* s8){
  int w = threadIdx.x>>6;
  v = wave_max64(v);
  if ((threadIdx.x&63)==0) s8[w] = v;
  __syncthreads();
  float r = s8[0];
  #pragma unroll
  for (int q=1;q<8;q++) r = fmaxf(r, s8[q]);
  __syncthreads();
  return r;
}

// ---------------- init: copy state, zero buffers, transpose weights ----------------
__global__ __launch_bounds__(256) void k_init(P p){
  int bid = blockIdx.x, tid = threadIdx.x;
  if (bid < 32){
    int gid = bid*256 + tid;
    const float4* src = (const float4*)(p.mem0 + (size_t)gid*Mq);
    float4* dst = (float4*)(p.memv + (size_t)gid*Mq);
    float s = 0.f;
    #pragma unroll 8
    for (int c=0;c<32;c++){ float4 v = src[c]; dst[c]=v; s += dot4(v,v); }
    p.norms[gid] = sqrtf(s);
  } else if (bid < 224){
    float4* L = (float4*)p.link;
    int idx = (bid-32)*256 + tid; int stride = 192*256;
    float4 z4 = make_float4(0.f,0.f,0.f,0.f);
    for (int i=idx; i<(Bq*Nq*Nq)/4; i+=stride) L[i] = z4;
  } else if (bid == 224){
    for (int i=tid;i<Bq*Nq;i+=256){ p.usage[i]=0.f; p.prec0[i]=0.f; p.prec1[i]=0.f; p.ww[i]=0.f; }
    for (int i=tid;i<Bq*Rq*Nq;i+=256) p.rw[i]=0.f;
    for (int i=tid;i<Bq*Wq;i+=256) p.hs[i]=p.hs0[i];
  } else if (bid < 233){            // WbT: (768,128) -> (128,768)
    int idx=(bid-225)*256+tid, stride=8*256;
    for (int k=idx;k<DINq*Wq;k+=stride){ int j=k/DINq, i=k%DINq; p.WbT[k]=p.Wb[i*Wq+j]; }
  } else if (bid < 235){
    int idx=(bid-233)*256+tid, stride=2*256;
    for (int k=idx;k<Wq*Wq;k+=stride){ int j=k/Wq, i=k%Wq; p.Wff1T[k]=p.Wff1[i*Wq+j]; }
  } else if (bid < 237){
    int idx=(bid-235)*256+tid, stride=2*256;
    for (int k=idx;k<Wq*Wq;k+=stride){ int j=k/Wq, i=k%Wq; p.Wff2T[k]=p.Wff2[i*Wq+j]; }
  } else if (bid < 239){
    int idx=(bid-237)*256+tid, stride=2*256;
    for (int k=idx;k<Wq*Wq;k+=stride){ int j=k/Wq, i=k%Wq; p.WtaT[k]=p.Wta[i*Wq+j]; }
  } else if (bid < 241){
    int idx=(bid-239)*256+tid, stride=2*256;
    for (int k=idx;k<Wq*Wq;k+=stride){ int j=k/Wq, i=k%Wq; p.WtbT[k]=p.Wtb[i*Wq+j]; }
  } else if (bid < 243){
    int idx=(bid-241)*256+tid, stride=2*256;
    for (int k=idx;k<Wq*Wq;k+=stride){ int j=k/Wq, i=k%Wq; p.WvT[k]=p.Wv[i*Wq+j]; }
  } else if (bid < 247){            // WrT: (512,128) -> (128,512)
    int idx=(bid-243)*256+tid, stride=4*256;
    for (int k=idx;k<Rq*Wq*Wq;k+=stride){ int j=k/(Rq*Wq), i=k%(Rq*Wq); p.WrT[k]=p.Wr[i*Wq+j]; }
  } else if (bid < 255){            // WxiT: (128,919) -> (919,128)
    int idx=(bid-247)*256+tid, stride=8*256;
    for (int k=idx;k<919*Wq;k+=stride){ int f=k/Wq, i=k%Wq; p.WxiT[k]=p.Wxi[i*919+f]; }
  }
}

// ============ k_A: per-batch front-end. One block per batch b. ============
// rw(t-1) combine -> reads(t-1) -> y(t-1) -> z(t) -> hs(t) -> xi(t) -> addr(t)
// Called with t==Tq as the tail (emits y(T-1) only).
__global__ __launch_bounds__(512) void k_A(P p, int t){
  const int b = blockIdx.x, tid = threadIdx.x;
  const bool fin = (t == Tq);
  __shared__ float rwl[Rq*Nq];        // rw(t-1), persists through addr
  __shared__ float inv[DINq];         // z input: [x(128) | reads(512) | keep*hs(128)]
  __shared__ float hprev[Wq];
  __shared__ float zl[Wq];
  __shared__ float hsl[Wq];
  __shared__ float acc4[4*Wq];
  __shared__ float key[Wq];
  __shared__ float xisc[32];          // xi scalars 896..918
  __shared__ float wcas[Nq];
  __shared__ float uarr[Nq];
  __shared__ float cp[Nq];
  __shared__ int   sidx[Nq];
  __shared__ float s8[8];

  const float* xold = p.xi + (size_t)b*XIPq;   // xi(t-1)
  // ---- A1: rw(t-1) = modes-combine(bw, rca, fw) ----
  if (t > 0){
    int k = tid;
    #pragma unroll
    for (int r=0;r<Rq;r++){
      float m0=xold[904+r*3], m1=xold[905+r*3], m2=xold[906+r*3];
      float mm=fmaxf(m0,fmaxf(m1,m2));
      float e0=expf(m0-mm), e1=expf(m1-mm), e2=expf(m2-mm);
      float es=e0+e1+e2;
      float fwv=0.f;
      #pragma unroll
      for (int g=0;g<8;g++) fwv += p.fwpart[(((size_t)(b*8+g))*Rq+r)*Nq + k];
      float bwv = p.bw [((size_t)b*Rq+r)*Nq + k];
      float rcav= p.rca[((size_t)b*Rq+r)*Nq + k];
      float rwv = (e0*bwv + e1*rcav + e2*fwv)/es;
      rwl[r*Nq+k] = rwv;
      p.rw[((size_t)b*Rq+r)*Nq + k] = rwv;
    }
  } else {
    #pragma unroll
    for (int r=0;r<Rq;r++) rwl[r*Nq+tid] = 0.f;
  }
  if (tid < Wq) hprev[tid] = p.hs[b*Wq + tid];
  __syncthreads();
  // ---- A2: reads(t-1) = rw(t-1) @ memv ----
  {
    int r = tid>>7, m = tid&127;
    const float* rl = rwl + r*Nq;
    const float* mb = p.memv + (size_t)b*Nq*Mq + m;
    float racc = 0.f;
    if (t > 0){
      #pragma unroll 8
      for (int n=0;n<Nq;n++) racc += rl[n]*mb[(size_t)n*Mq];
    }
    inv[Wq + tid] = racc;
  }
  __syncthreads();
  // ---- A3: y(t-1) = hs(t-1)@Wv + reads(t-1)@Wr + bv + br ----
  if (t > 0){
    int j = tid>>2, q = tid&3;
    const float4* wv4 = (const float4*)(p.WvT + (size_t)j*Wq);
    const float4* wr4 = (const float4*)(p.WrT + (size_t)j*(Rq*Wq));
    const float4* h4  = (const float4*)hprev;
    const float4* rd4 = (const float4*)(inv + Wq);
    float ya = 0.f;
    #pragma unroll
    for (int c=q;c<32;c+=4)  ya += dot4(wv4[c], h4[c]);
    #pragma unroll
    for (int c=q;c<128;c+=4) ya += dot4(wr4[c], rd4[c]);
    ya += __shfl_xor(ya,1,4); ya += __shfl_xor(ya,2,4);
    if (q==0) p.out[((size_t)b*Tq + (t-1))*Wq + j] = ya + p.bv[j] + p.br[j];
  }
  if (fin) return;

  float keep = 1.f - (float)p.rst[b*Tq + t];
  if (tid < Wq){
    inv[tid] = p.X[((size_t)b*Tq + t)*Wq + tid];
    inv[Wq + Rq*Wq + tid] = keep*hprev[tid];
  }
  __syncthreads();
  // ---- A4: z = silu(inv @ Wb + bb) ----
  {
    int j = tid>>2, q = tid&3;
    const float4* w4  = (const float4*)(p.WbT + (size_t)j*DINq);
    const float4* in4 = (const float4*)inv;
    float a = 0.f;
    #pragma unroll
    for (int c=q;c<192;c+=4) a += dot4(w4[c], in4[c]);
    a += __shfl_xor(a,1,4); a += __shfl_xor(a,2,4);
    if (q==0){ float aa = a + p.bb[j]; zl[j] = aa*sigf(aa); }
  }
  __syncthreads();
  // ---- A5: hs = ff1*(1-ti)+ti*ff2 ----
  {
    int which = tid>>7, j = tid&127;
    const float* Ws0 = (which==0)? p.Wff1T : (which==1)? p.Wff2T : (which==2)? p.WtaT : p.WtbT;
    const float4* w4 = (const float4*)(Ws0 + (size_t)j*Wq);
    const float4* z4 = (const float4*)zl;
    float a = 0.f;
    #pragma unroll 8
    for (int c=0;c<32;c++) a += dot4(w4[c], z4[c]);
    acc4[which*Wq + j] = a;
  }
  __syncthreads();
  if (tid < Wq){
    float a1 = acc4[tid]      + p.bff1[tid];
    float a2 = acc4[Wq+tid]   + p.bff2[tid];
    float aa = acc4[2*Wq+tid] + p.bta[tid];
    float ab = acc4[3*Wq+tid] + p.btb[tid];
    float ti = sigf(aa*(float)t + ab);
    float h = a1*(1.f-ti) + ti*a2;
    hsl[tid] = h;
    p.hs[b*Wq+tid] = h;
    p.out[BTWq + ((size_t)b*Tq + t)*Wq + tid] = h;
  }
  __syncthreads();
  // ---- A6: xi = hs @ Wxi + bxi ----
  {
    const float4* h4 = (const float4*)hsl;
    int f = tid;
    const float4* w4 = (const float4*)(p.WxiT + (size_t)f*Wq);
    float a = p.bxi[f];
    #pragma unroll 8
    for (int c=0;c<32;c++) a += dot4(w4[c], h4[c]);
    p.xi[(size_t)b*XIPq + f] = a;
    int f2 = 512 + tid;
    if (f2 < 919){
      const float4* w42 = (const float4*)(p.WxiT + (size_t)f2*Wq);
      float a2 = p.bxi[f2];
      #pragma unroll 8
      for (int c=0;c<32;c++) a2 += dot4(w42[c], h4[c]);
      p.xi[(size_t)b*XIPq + f2] = a2;
      if (tid < Wq) key[tid] = a2;          // write_key = xi[512..640)
      if (f2 >= 896) xisc[f2-896] = a2;     // scalars
    }
  }
  __syncthreads();
  // ---- A7: addr — wca, usage, rank-sort, cumprod, alloc, ww, prec ----
  {
    float kk = (tid<Wq)? key[tid]*key[tid] : 0.f;
    float kn = sqrtf(blk_sum(kk, s8));
    int n = tid;
    const float4* k4 = (const float4*)key;
    const float4* mrow = (const float4*)(p.memv + ((size_t)b*Nq+n)*Mq);
    float d = 0.f;
    #pragma unroll 8
    for (int c=0;c<32;c++) d += dot4(k4[c], mrow[c]);
    float mn = p.norms[b*Nq+n];
    float sim = (keep*d)/(kn*(keep*mn) + 1e-6f);
    float wstr = oneplusf(xisc[20]);
    float v = wstr*sim;
    float mx = blk_max(v, s8);
    float e = expf(v-mx);
    float se = blk_sum(e, s8);
    wcas[n] = e/se;
    float ret = 1.f;
    #pragma unroll
    for (int r=0;r<Rq;r++) ret *= 1.f - sigf(xisc[r])*rwl[r*Nq+n];
    float uo = p.usage[b*Nq+n], pw = p.ww[b*Nq+n];
    float u = (uo + pw - uo*pw)*ret;
    p.usage[b*Nq+n] = u;
    uarr[n] = u;
    __syncthreads();
    // stable ascending rank: #{j: u_j<u_i} + #{j<i: u_j==u_i}
    int rank = 0;
    const float4* u4 = (const float4*)uarr;
    #pragma unroll 8
    for (int jj=0;jj<128;jj++){
      float4 vv = u4[jj]; int j0=jj*4;
      rank += (vv.x<u)||(vv.x==u && (j0+0)<n);
      rank += (vv.y<u)||(vv.y==u && (j0+1)<n);
      rank += (vv.z<u)||(vv.z==u && (j0+2)<n);
      rank += (vv.w<u)||(vv.w==u && (j0+3)<n);
    }
    sidx[rank] = n;
    __syncthreads();
    int si = sidx[n];                 // orig index of rank-n element
    float sv = uarr[si];
    int w = tid>>6, l = tid&63;
    float x = sv;
    #pragma unroll
    for (int dd=1;dd<64;dd<<=1){
      float pr = __shfl_up(x, dd, 64);
      if (l>=dd) x *= pr;
    }
    if (l==63) s8[w] = x;
    __syncthreads();
    float woff = 1.f;
    #pragma unroll
    for (int q=0;q<8;q++) if (q<w) woff *= s8[q];
    x *= woff;
    cp[n] = x;
    __syncthreads();
    float alloc = (1.f - u)*cp[si];   // reference's cp[si[k]] indexing
    float ag = sigf(xisc[21]), wg = sigf(xisc[22]);
    float wwv = wg*(ag*alloc + (1.f-ag)*wcas[n]);
    p.ww[b*Nq+n] = wwv;
    float wsum = blk_sum(wwv, s8);
    const float* po = (t&1)? p.prec1 : p.prec0;
    float*       pn = (t&1)? p.prec0 : p.prec1;
    pn[b*Nq+n] = (1.f - wsum)*po[b*Nq+n] + wwv;
  }
}

// ============ k_B: link update + fw/bw partials (0..127) || mem update + rca (128..143) ============
__global__ __launch_bounds__(512) void k_B(P p, int t){
  int bid = blockIdx.x, tid = threadIdx.x;
  const float* po = (t&1)? p.prec1 : p.prec0;
  __shared__ float fwacc[Rq*Nq];
  __shared__ float keyv[Rq*Wq];
  __shared__ float wv[Wq], er[Wq];
  __shared__ float s8[8];
  if (bid < 128){
    int b = bid>>3, g = bid&7;           // 64 rows per block
    #pragma unroll
    for (int i=0;i<4;i++) fwacc[i*512+tid] = 0.f;
    __syncthreads();
    int w = tid>>6, l = tid&63, c0 = l*8;
    const float* wwb = p.ww + b*Nq;
    const float* pob = po + b*Nq;
    float ww8[8], pc8[8], pr8[Rq][8];
    *(float4*)&ww8[0] = *(const float4*)(wwb + c0);
    *(float4*)&ww8[4] = *(const float4*)(wwb + c0 + 4);
    *(float4*)&pc8[0] = *(const float4*)(pob + c0);
    *(float4*)&pc8[4] = *(const float4*)(pob + c0 + 4);
    #pragma unroll
    for (int r=0;r<Rq;r++){
      *(float4*)&pr8[r][0] = *(const float4*)(p.rw + ((size_t)b*Rq+r)*Nq + c0);
      *(float4*)&pr8[r][4] = *(const float4*)(p.rw + ((size_t)b*Rq+r)*Nq + c0 + 4);
    }
    float fa[Rq][8];
    #pragma unroll
    for (int r=0;r<Rq;r++)
      #pragma unroll
      for (int q=0;q<8;q++) fa[r][q]=0.f;
    for (int rr=0; rr<8; rr++){
      int n = g*64 + w*8 + rr;
      float wwn = wwb[n];
      float prn[Rq];
      #pragma unroll
      for (int r=0;r<Rq;r++) prn[r] = p.rw[((size_t)b*Rq+r)*Nq + n];
      size_t row = ((size_t)b*Nq + n)*Nq;
      float4 La = *(const float4*)(p.link + row + c0);
      float4 Lb = *(const float4*)(p.link + row + c0 + 4);
      float vv[8] = {La.x,La.y,La.z,La.w,Lb.x,Lb.y,Lb.z,Lb.w};
      float bwp[Rq] = {0.f,0.f,0.f,0.f};
      #pragma unroll
      for (int q=0;q<8;q++){
        float nv = (1.f - wwn - ww8[q])*vv[q] + wwn*pc8[q];
        if (c0 + q == n) nv = 0.f;
        vv[q] = nv;
        #pragma unroll
        for (int r=0;r<Rq;r++){ fa[r][q] += prn[r]*nv; bwp[r] += pr8[r][q]*nv; }
      }
      *(float4*)(p.link + row + c0)     = make_float4(vv[0],vv[1],vv[2],vv[3]);
      *(float4*)(p.link + row + c0 + 4) = make_float4(vv[4],vv[5],vv[6],vv[7]);
      #pragma unroll
      for (int m=1;m<64;m<<=1)
        #pragma unroll
        for (int r=0;r<Rq;r++) bwp[r] += __shfl_xor(bwp[r], m, 64);
      if (l==0){
        #pragma unroll
        for (int r=0;r<Rq;r++) p.bw[((size_t)b*Rq+r)*Nq + n] = bwp[r];
      }
    }
    #pragma unroll
    for (int r=0;r<Rq;r++)
      #pragma unroll
      for (int q=0;q<8;q++) atomicAdd(&fwacc[r*Nq + c0 + q], fa[r][q]);
    __syncthreads();
    #pragma unroll
    for (int i=0;i<4;i++){
      int id = i*512 + tid; int r = id>>9, k = id&511;
      p.fwpart[(((size_t)(b*8+g))*Rq + r)*Nq + k] = fwacc[id];
    }
  } else {
    int b = bid - 128;
    const float* xib = p.xi + (size_t)b*XIPq;
    keyv[tid] = xib[tid];                 // raw read keys 0..511
    if (tid < Wq){ wv[tid] = xib[640+tid]; er[tid] = sigf(xib[768+tid]); }
    __syncthreads();
    float kn4[4], rstr[4];
    #pragma unroll
    for (int r=0;r<Rq;r++){
      float kk = (tid<Wq)? keyv[r*Wq+tid]*keyv[r*Wq+tid] : 0.f;
      kn4[r] = sqrtf(blk_sum(kk, s8));
      rstr[r] = oneplusf(xib[900+r]);
    }
    int n = tid;
    float keep = 1.f - (float)p.rst[b*Tq + t];
    float wwn = p.ww[b*Nq+n];
    float4* mrow = (float4*)(p.memv + ((size_t)b*Nq+n)*Mq);
    const float4* er4 = (const float4*)er;
    const float4* wv4 = (const float4*)wv;
    const float4* k40 = (const float4*)(keyv);
    const float4* k41 = (const float4*)(keyv+128);
    const float4* k42 = (const float4*)(keyv+256);
    const float4* k43 = (const float4*)(keyv+384);
    float s = 0.f, d0=0.f, d1=0.f, d2=0.f, d3=0.f;
    #pragma unroll 4
    for (int c=0;c<32;c++){
      float4 mv = mrow[c], e4 = er4[c], w4 = wv4[c];
      mv.x = mv.x*keep*(1.f - wwn*e4.x) + wwn*w4.x;
      mv.y = mv.y*keep*(1.f - wwn*e4.y) + wwn*w4.y;
      mv.z = mv.z*keep*(1.f - wwn*e4.z) + wwn*w4.z;
      mv.w = mv.w*keep*(1.f - wwn*e4.w) + wwn*w4.w;
      s += dot4(mv,mv);
      d0 += dot4(k40[c], mv); d1 += dot4(k41[c], mv);
      d2 += dot4(k42[c], mv); d3 += dot4(k43[c], mv);
      mrow[c] = mv;
    }
    float mn = sqrtf(s);
    p.norms[b*Nq+n] = mn;
    float dd[4] = {d0,d1,d2,d3};
    #pragma unroll
    for (int r=0;r<Rq;r++){
      float v = rstr[r] * (dd[r] / (kn4[r]*mn + 1e-6f));
      float mx = blk_max(v, s8);
      float e = expf(v - mx);
      float se = blk_sum(e, s8);
      p.rca[((size_t)(b*Rq+r))*Nq + n] = e/se;
    }
  }
}

extern "C" void kernel_launch(void* const* d_in, const int* in_sizes, int n_in,
                              void* d_out, int out_size, void* d_ws, size_t ws_size,
                              hipStream_t stream){
  (void)in_sizes; (void)n_in; (void)out_size; (void)ws_size;
  P p;
  p.X    = (const float*)d_in[0];
  p.hs0  = (const float*)d_in[1];
  p.mem0 = (const float*)d_in[2];
  p.rst  = (const int*)d_in[3];
  p.Wb   = (const float*)d_in[4];  p.bb   = (const float*)d_in[5];
  p.Wff1 = (const float*)d_in[6];  p.bff1 = (const float*)d_in[7];
  p.Wff2 = (const float*)d_in[8];  p.bff2 = (const float*)d_in[9];
  p.Wta  = (const float*)d_in[10]; p.bta  = (const float*)d_in[11];
  p.Wtb  = (const float*)d_in[12]; p.btb  = (const float*)d_in[13];
  p.Wv   = (const float*)d_in[14]; p.bv   = (const float*)d_in[15];
  p.Wr   = (const float*)d_in[16]; p.br   = (const float*)d_in[17];
  p.Wxi  = (const float*)d_in[18]; p.bxi  = (const float*)d_in[19];
  p.out = (float*)d_out;
  float* ws = (float*)d_ws;
  size_t o = 0;
  p.memv   = ws + o; o += (size_t)Bq*Nq*Mq;       // 1,048,576
  p.link   = ws + o; o += (size_t)Bq*Nq*Nq;       // 4,194,304
  p.fwpart = ws + o; o += (size_t)Bq*8*Rq*Nq;     //   262,144
  p.bw     = ws + o; o += (size_t)Bq*Rq*Nq;
  p.rw     = ws + o; o += (size_t)Bq*Rq*Nq;
  p.rca    = ws + o; o += (size_t)Bq*Rq*Nq;
  p.hs     = ws + o; o += (size_t)Bq*Wq;
  p.ww     = ws + o; o += (size_t)Bq*Nq;
  p.usage  = ws + o; o += (size_t)Bq*Nq;
  p.prec0  = ws + o; o += (size_t)Bq*Nq;
  p.prec1  = ws + o; o += (size_t)Bq*Nq;
  p.norms  = ws + o; o += (size_t)Bq*Nq;
  p.xi     = ws + o; o += (size_t)Bq*XIPq;
  p.WbT    = ws + o; o += (size_t)DINq*Wq;
  p.Wff1T  = ws + o; o += (size_t)Wq*Wq;
  p.Wff2T  = ws + o; o += (size_t)Wq*Wq;
  p.WtaT   = ws + o; o += (size_t)Wq*Wq;
  p.WtbT   = ws + o; o += (size_t)Wq*Wq;
  p.WvT    = ws + o; o += (size_t)Wq*Wq;
  p.WrT    = ws + o; o += (size_t)Rq*Wq*Wq;
  p.WxiT   = ws + o; o += (size_t)919*Wq;

  hipLaunchKernelGGL(k_init, dim3(320), dim3(256), 0, stream, p);
  for (int t=0; t<Tq; t++){
    hipLaunchKernelGGL(k_A, dim3(16),  dim3(512), 0, stream, p, t);
    hipLaunchKernelGGL(k_B, dim3(144), dim3(512), 0, stream, p, t);
  }
  hipLaunchKernelGGL(k_A, dim3(16), dim3(512), 0, stream, p, Tq);  // tail: y(T-1)
}

// Round 4
// 2705.335 us; speedup vs baseline: 1.9675x; 1.3533x over previous
//
#include <hip/hip_runtime.h>
#include <math.h>

#define Bq 16
#define Tq 32
#define Wq 128
#define Rq 4
#define Nq 512
#define Mq 128
#define DINq 768
#define XIPq 920
#define BTWq (Bq*Tq*Wq)

struct P {
  const float *X, *hs0, *mem0;
  const int *rst;
  const float *Wb,*bb,*Wff1,*bff1,*Wff2,*bff2,*Wta,*bta,*Wtb,*btb,*Wv,*bv,*Wr,*br,*Wxi,*bxi;
  float *out;
  float *memv,*memvT,*link,*fwpart,*bw,*rw,*rca,*hs,*reads,*z,*ww,*usage,*prec0,*prec1,*norms,*xi;
  float *WbT,*Wff1T,*Wff2T,*WtaT,*WtbT,*WvT,*WrT,*WxiT;
};

__device__ __forceinline__ float dot4(float4 a, float4 b){
  return a.x*b.x + a.y*b.y + a.z*b.z + a.w*b.w;
}
__device__ __forceinline__ float sigf(float x){ return 1.f/(1.f+expf(-x)); }
__device__ __forceinline__ float oneplusf(float x){ return 1.f + log1pf(expf(x) + 1e-6f); }

__device__ __forceinline__ float wave_sum64(float v){
  #pragma unroll
  for (int m=32;m>=1;m>>=1) v += __shfl_xor(v, m, 64);
  return v;
}
__device__ __forceinline__ float wave_max64(float v){
  #pragma unroll
  for (int m=32;m>=1;m>>=1) v = fmaxf(v, __shfl_xor(v, m, 64));
  return v;
}
__device__ __forceinline__ float blk_sum(float v, float* s8){
  int w = threadIdx.x>>6;
  v = wave_sum64(v);
  if ((threadIdx.x&63)==0) s8[w] = v;
  __syncthreads();
  float r = s8[0]+s8[1]+s8[2]+s8[3]+s8[4]+s8[5]+s8[6]+s8[7];
  __syncthreads();
  return r;
}
__device__ __forceinline__ float blk_max(float v, float* s8){
  int w = threadIdx.x>>6;
  v = wave_max64(v);
  if ((threadIdx.x&63)==0) s8[w] = v;
  __syncthreads();
  float r = s8[0];
  #pragma unroll
  for (int q=1;q<8;q++) r = fmaxf(r, s8[q]);
  __syncthreads();
  return r;
}

// ---------------- init: copy state, zero buffers, transpose weights ----------------
__global__ __launch_bounds__(256) void k_init(P p){
  int bid = blockIdx.x, tid = threadIdx.x;
  if (bid < 32){
    int gid = bid*256 + tid;                 // (b,n): 8192 rows
    int b = gid >> 9, n = gid & 511;
    const float4* src = (const float4*)(p.mem0 + (size_t)gid*Mq);
    float4* dst = (float4*)(p.memv + (size_t)gid*Mq);
    float* mT = p.memvT + (size_t)b*Nq*Mq;
    float s = 0.f;
    #pragma unroll 8
    for (int c=0;c<32;c++){
      float4 v = src[c]; dst[c]=v; s += dot4(v,v);
      mT[(4*c+0)*Nq + n] = v.x; mT[(4*c+1)*Nq + n] = v.y;
      mT[(4*c+2)*Nq + n] = v.z; mT[(4*c+3)*Nq + n] = v.w;
    }
    p.norms[gid] = sqrtf(s);
  } else if (bid < 224){
    float4* L = (float4*)p.link;
    int idx = (bid-32)*256 + tid; int stride = 192*256;
    float4 z4 = make_float4(0.f,0.f,0.f,0.f);
    for (int i=idx; i<(Bq*Nq*Nq)/4; i+=stride) L[i] = z4;
  } else if (bid == 224){
    for (int i=tid;i<Bq*Nq;i+=256){ p.usage[i]=0.f; p.prec0[i]=0.f; p.prec1[i]=0.f; p.ww[i]=0.f; }
    for (int i=tid;i<Bq*Rq*Nq;i+=256) p.rw[i]=0.f;
    for (int i=tid;i<Bq*Rq*Wq;i+=256) p.reads[i]=0.f;
    for (int i=tid;i<Bq*Wq;i+=256) p.hs[i]=p.hs0[i];
  } else if (bid < 233){            // WbT: (768,128) -> (128,768)
    int idx=(bid-225)*256+tid, stride=8*256;
    for (int k=idx;k<DINq*Wq;k+=stride){ int j=k/DINq, i=k%DINq; p.WbT[k]=p.Wb[i*Wq+j]; }
  } else if (bid < 235){
    int idx=(bid-233)*256+tid, stride=2*256;
    for (int k=idx;k<Wq*Wq;k+=stride){ int j=k/Wq, i=k%Wq; p.Wff1T[k]=p.Wff1[i*Wq+j]; }
  } else if (bid < 237){
    int idx=(bid-235)*256+tid, stride=2*256;
    for (int k=idx;k<Wq*Wq;k+=stride){ int j=k/Wq, i=k%Wq; p.Wff2T[k]=p.Wff2[i*Wq+j]; }
  } else if (bid < 239){
    int idx=(bid-237)*256+tid, stride=2*256;
    for (int k=idx;k<Wq*Wq;k+=stride){ int j=k/Wq, i=k%Wq; p.WtaT[k]=p.Wta[i*Wq+j]; }
  } else if (bid < 241){
    int idx=(bid-239)*256+tid, stride=2*256;
    for (int k=idx;k<Wq*Wq;k+=stride){ int j=k/Wq, i=k%Wq; p.WtbT[k]=p.Wtb[i*Wq+j]; }
  } else if (bid < 243){
    int idx=(bid-241)*256+tid, stride=2*256;
    for (int k=idx;k<Wq*Wq;k+=stride){ int j=k/Wq, i=k%Wq; p.WvT[k]=p.Wv[i*Wq+j]; }
  } else if (bid < 247){            // WrT: (512,128) -> (128,512)
    int idx=(bid-243)*256+tid, stride=4*256;
    for (int k=idx;k<Rq*Wq*Wq;k+=stride){ int j=k/(Rq*Wq), i=k%(Rq*Wq); p.WrT[k]=p.Wr[i*Wq+j]; }
  } else if (bid < 255){            // WxiT: (128,919) -> (919,128)
    int idx=(bid-247)*256+tid, stride=8*256;
    for (int k=idx;k<919*Wq;k+=stride){ int f=k/Wq, i=k%Wq; p.WxiT[k]=p.Wxi[i*919+f]; }
  }
}

// ======== k1: rw(t-1) combine + reads(t-1). 64 blocks (b*4+r), 512 thr ========
__global__ __launch_bounds__(512) void k1(P p, int t){
  int b = blockIdx.x>>2, r = blockIdx.x&3, tid = threadIdx.x;
  __shared__ float rwl[Nq];
  const float* xib = p.xi + (size_t)b*XIPq;
  float m0=xib[904+r*3], m1=xib[905+r*3], m2=xib[906+r*3];
  float mm=fmaxf(m0,fmaxf(m1,m2));
  float e0=expf(m0-mm), e1=expf(m1-mm), e2=expf(m2-mm);
  float es=e0+e1+e2;
  {
    int k = tid;
    float fwv=0.f;
    #pragma unroll
    for (int g=0;g<8;g++) fwv += p.fwpart[(((size_t)(b*8+g))*Rq+r)*Nq + k];
    float bwv = p.bw [((size_t)b*Rq+r)*Nq + k];
    float rcav= p.rca[((size_t)b*Rq+r)*Nq + k];
    float rwv = (e0*bwv + e1*rcav + e2*fwv)/es;
    rwl[k] = rwv;
    p.rw[((size_t)b*Rq+r)*Nq + k] = rwv;
  }
  __syncthreads();
  // reads[m] = sum_n rwl[n]*memvT[b][m][n]; 4 threads per m
  int m = tid>>2, q = tid&3;
  const float4* mT = (const float4*)(p.memvT + ((size_t)b*Mq + m)*Nq + q*128);
  const float4* rl = (const float4*)(rwl + q*128);
  float a0=0.f, a1=0.f;
  #pragma unroll 8
  for (int c=0;c<32;c+=2){ a0 += dot4(mT[c], rl[c]); a1 += dot4(mT[c+1], rl[c+1]); }
  float a = a0+a1;
  a += __shfl_xor(a,1,4); a += __shfl_xor(a,2,4);
  if (q==0) p.reads[b*Rq*Wq + r*Wq + m] = a;
}

// ======== k2: z(t) (blocks 0..127) || y(t-1) (blocks 128..255). 256 thr ========
__global__ __launch_bounds__(256) void k2(P p, int t){
  int bid = blockIdx.x, tid = threadIdx.x;
  int b = tid>>4, l = tid&15;
  if (bid < 128){
    if (t == Tq) return;
    int j = bid;
    float keep = 1.f - (float)p.rst[b*Tq + t];
    const float4* w4 = (const float4*)(p.WbT + (size_t)j*DINq);
    const float4* x4 = (const float4*)(p.X + ((size_t)(b*Tq+t))*Wq);
    const float4* r4 = (const float4*)(p.reads + (size_t)b*Rq*Wq);
    const float4* h4 = (const float4*)(p.hs + (size_t)b*Wq);
    float acc = 0.f;
    #pragma unroll
    for (int k=0;k<12;k++){
      int c = l + k*16;
      float4 iv;
      if (c < 32) iv = x4[c];
      else if (c < 160) iv = r4[c-32];
      else { iv = h4[c-160]; iv.x*=keep; iv.y*=keep; iv.z*=keep; iv.w*=keep; }
      acc += dot4(w4[c], iv);
    }
    acc += __shfl_xor(acc,1,16); acc += __shfl_xor(acc,2,16);
    acc += __shfl_xor(acc,4,16); acc += __shfl_xor(acc,8,16);
    if (l==0){ float a = acc + p.bb[j]; p.z[b*Wq+j] = a*sigf(a); }
  } else {
    if (t == 0) return;
    int j = bid - 128;
    const float4* wv4 = (const float4*)(p.WvT + (size_t)j*Wq);
    const float4* wr4 = (const float4*)(p.WrT + (size_t)j*(Rq*Wq));
    const float4* h4  = (const float4*)(p.hs + (size_t)b*Wq);
    const float4* r4  = (const float4*)(p.reads + (size_t)b*Rq*Wq);
    float acc = 0.f;
    #pragma unroll
    for (int k=0;k<10;k++){
      int c = l + k*16;
      acc += (c < 32) ? dot4(wv4[c], h4[c]) : dot4(wr4[c-32], r4[c-32]);
    }
    acc += __shfl_xor(acc,1,16); acc += __shfl_xor(acc,2,16);
    acc += __shfl_xor(acc,4,16); acc += __shfl_xor(acc,8,16);
    if (l==0) p.out[((size_t)b*Tq + (t-1))*Wq + j] = acc + p.bv[j] + p.br[j];
  }
}

// ======== k3: hs(t). 128 blocks (j), 256 thr ========
__global__ __launch_bounds__(256) void k3(P p, int t){
  int j = blockIdx.x, tid = threadIdx.x;
  int b = tid>>4, l = tid&15;
  const float4* z4 = (const float4*)(p.z + b*Wq);
  const float4* w1 = (const float4*)(p.Wff1T + j*Wq);
  const float4* w2 = (const float4*)(p.Wff2T + j*Wq);
  const float4* wa = (const float4*)(p.WtaT + j*Wq);
  const float4* wb = (const float4*)(p.WtbT + j*Wq);
  float4 za = z4[l], zb = z4[l+16];
  float a1 = dot4(w1[l],za) + dot4(w1[l+16],zb);
  float a2 = dot4(w2[l],za) + dot4(w2[l+16],zb);
  float aa = dot4(wa[l],za) + dot4(wa[l+16],zb);
  float ab = dot4(wb[l],za) + dot4(wb[l+16],zb);
  #pragma unroll
  for (int m=1;m<16;m<<=1){
    a1 += __shfl_xor(a1,m,16); a2 += __shfl_xor(a2,m,16);
    aa += __shfl_xor(aa,m,16); ab += __shfl_xor(ab,m,16);
  }
  if (l==0){
    a1 += p.bff1[j]; a2 += p.bff2[j]; aa += p.bta[j]; ab += p.btb[j];
    float ti = sigf(aa*(float)t + ab);
    float h = a1*(1.f-ti) + ti*a2;
    p.hs[b*Wq+j] = h;
    p.out[BTWq + ((size_t)b*Tq + t)*Wq + j] = h;
  }
}

// ======== k45: addr (blocks 0..15) || xi features (16..111). 512 thr ========
__global__ __launch_bounds__(512) void k45(P p, int t){
  int bid = blockIdx.x, tid = threadIdx.x;
  if (bid >= 16){
    // xi features: read keys (0..511), write_vec (640..767), erase (768..895)
    int i = bid - 16;                  // 0..95, 8 features each
    int b = tid>>5, l = tid&31;
    const float4* h4 = (const float4*)(p.hs + b*Wq);
    float4 hv = h4[l];
    #pragma unroll
    for (int q=0;q<8;q++){
      int idx = i*8 + q;
      int f = (idx<512)? idx : idx+128;
      const float4* w4 = (const float4*)(p.WxiT + (size_t)f*Wq);
      float acc = dot4(w4[l], hv);
      #pragma unroll
      for (int m=1;m<32;m<<=1) acc += __shfl_xor(acc,m,32);
      if (l==0) p.xi[(size_t)b*XIPq + f] = acc + p.bxi[f];
    }
    return;
  }
  int b = bid;
  __shared__ float hsb[Wq];
  __shared__ float key[Wq];
  __shared__ float xisc[32];
  __shared__ float wcas[Nq];
  __shared__ float uarr[Nq];
  __shared__ float cp[Nq];
  __shared__ int   sidx[Nq];
  __shared__ float s8[8];
  if (tid < 32) ((float4*)hsb)[tid] = ((const float4*)(p.hs + b*Wq))[tid];
  __syncthreads();
  if (tid < 151){                      // write_key 512..639 + scalars 896..918
    int f = (tid<128)? (512+tid) : (896 + (tid-128));
    const float4* w4 = (const float4*)(p.WxiT + (size_t)f*Wq);
    const float4* hh = (const float4*)hsb;
    float acc = p.bxi[f];
    #pragma unroll 8
    for (int c=0;c<32;c++) acc += dot4(w4[c], hh[c]);
    if (tid < 128) key[tid] = acc;
    else { xisc[tid-128] = acc; p.xi[(size_t)b*XIPq + f] = acc; }
  }
  __syncthreads();
  float keep = 1.f - (float)p.rst[b*Tq + t];
  float kk = (tid<Wq)? key[tid]*key[tid] : 0.f;
  float kn = sqrtf(blk_sum(kk, s8));
  int n = tid;
  // wca dot via memvT: coalesced across threads
  const float* mT = p.memvT + (size_t)b*Nq*Mq + n;
  float d = 0.f;
  #pragma unroll 8
  for (int m=0;m<Mq;m++) d += key[m]*mT[(size_t)m*Nq];
  float mn = p.norms[b*Nq+n];
  float sim = (keep*d)/(kn*(keep*mn) + 1e-6f);
  float wstr = oneplusf(xisc[20]);
  float v = wstr*sim;
  float mx = blk_max(v, s8);
  float e = expf(v-mx);
  float se = blk_sum(e, s8);
  wcas[n] = e/se;
  float ret = 1.f;
  #pragma unroll
  for (int r=0;r<Rq;r++) ret *= 1.f - sigf(xisc[r])*p.rw[((size_t)b*Rq+r)*Nq + n];
  float uo = p.usage[b*Nq+n], pw = p.ww[b*Nq+n];
  float u = (uo + pw - uo*pw)*ret;
  p.usage[b*Nq+n] = u;
  uarr[n] = u;
  __syncthreads();
  // stable ascending rank: #{j: u_j<u_i} + #{j<i: u_j==u_i}
  int rank = 0;
  const float4* u4 = (const float4*)uarr;
  #pragma unroll 8
  for (int jj=0;jj<128;jj++){
    float4 vv = u4[jj]; int j0=jj*4;
    rank += (vv.x<u)||(vv.x==u && (j0+0)<n);
    rank += (vv.y<u)||(vv.y==u && (j0+1)<n);
    rank += (vv.z<u)||(vv.z==u && (j0+2)<n);
    rank += (vv.w<u)||(vv.w==u && (j0+3)<n);
  }
  sidx[rank] = n;
  __syncthreads();
  int si = sidx[n];                 // orig index of rank-n element
  float sv = uarr[si];
  int w = tid>>6, l = tid&63;
  float x = sv;
  #pragma unroll
  for (int dd=1;dd<64;dd<<=1){
    float pr = __shfl_up(x, dd, 64);
    if (l>=dd) x *= pr;
  }
  if (l==63) s8[w] = x;
  __syncthreads();
  float woff = 1.f;
  #pragma unroll
  for (int q=0;q<8;q++) if (q<w) woff *= s8[q];
  x *= woff;
  cp[n] = x;
  __syncthreads();
  float alloc = (1.f - u)*cp[si];   // reference's cp[si[k]] indexing
  float ag = sigf(xisc[21]), wg = sigf(xisc[22]);
  float wwv = wg*(ag*alloc + (1.f-ag)*wcas[n]);
  p.ww[b*Nq+n] = wwv;
  float wsum = blk_sum(wwv, s8);
  const float* po = (t&1)? p.prec1 : p.prec0;
  float*       pn = (t&1)? p.prec0 : p.prec1;
  pn[b*Nq+n] = (1.f - wsum)*po[b*Nq+n] + wwv;
}

// ======== k6: link+fw/bw (0..127) || mem update + memvT + rca (128..143) ========
__global__ __launch_bounds__(512) void k6(P p, int t){
  int bid = blockIdx.x, tid = threadIdx.x;
  const float* po = (t&1)? p.prec1 : p.prec0;
  __shared__ float fwacc[Rq*Nq];
  __shared__ float keyv[Rq*Wq];
  __shared__ float wv[Wq], er[Wq];
  __shared__ float s8[8];
  if (bid < 128){
    int b = bid>>3, g = bid&7;           // 64 rows per block
    #pragma unroll
    for (int i=0;i<4;i++) fwacc[i*512+tid] = 0.f;
    __syncthreads();
    int w = tid>>6, l = tid&63, c0 = l*8;
    const float* wwb = p.ww + b*Nq;
    const float* pob = po + b*Nq;
    float ww8[8], pc8[8], pr8[Rq][8];
    *(float4*)&ww8[0] = *(const float4*)(wwb + c0);
    *(float4*)&ww8[4] = *(const float4*)(wwb + c0 + 4);
    *(float4*)&pc8[0] = *(const float4*)(pob + c0);
    *(float4*)&pc8[4] = *(const float4*)(pob + c0 + 4);
    #pragma unroll
    for (int r=0;r<Rq;r++){
      *(float4*)&pr8[r][0] = *(const float4*)(p.rw + ((size_t)b*Rq+r)*Nq + c0);
      *(float4*)&pr8[r][4] = *(const float4*)(p.rw + ((size_t)b*Rq+r)*Nq + c0 + 4);
    }
    float fa[Rq][8];
    #pragma unroll
    for (int r=0;r<Rq;r++)
      #pragma unroll
      for (int q=0;q<8;q++) fa[r][q]=0.f;
    for (int rr=0; rr<8; rr++){
      int n = g*64 + w*8 + rr;
      float wwn = wwb[n];
      float prn[Rq];
      #pragma unroll
      for (int r=0;r<Rq;r++) prn[r] = p.rw[((size_t)b*Rq+r)*Nq + n];
      size_t row = ((size_t)b*Nq + n)*Nq;
      float4 La = *(const float4*)(p.link + row + c0);
      float4 Lb = *(const float4*)(p.link + row + c0 + 4);
      float vv[8] = {La.x,La.y,La.z,La.w,Lb.x,Lb.y,Lb.z,Lb.w};
      float bwp[Rq] = {0.f,0.f,0.f,0.f};
      #pragma unroll
      for (int q=0;q<8;q++){
        float nv = (1.f - wwn - ww8[q])*vv[q] + wwn*pc8[q];
        if (c0 + q == n) nv = 0.f;
        vv[q] = nv;
        #pragma unroll
        for (int r=0;r<Rq;r++){ fa[r][q] += prn[r]*nv; bwp[r] += pr8[r][q]*nv; }
      }
      *(float4*)(p.link + row + c0)     = make_float4(vv[0],vv[1],vv[2],vv[3]);
      *(float4*)(p.link + row + c0 + 4) = make_float4(vv[4],vv[5],vv[6],vv[7]);
      #pragma unroll
      for (int m=1;m<64;m<<=1)
        #pragma unroll
        for (int r=0;r<Rq;r++) bwp[r] += __shfl_xor(bwp[r], m, 64);
      if (l==0){
        #pragma unroll
        for (int r=0;r<Rq;r++) p.bw[((size_t)b*Rq+r)*Nq + n] = bwp[r];
      }
    }
    #pragma unroll
    for (int r=0;r<Rq;r++)
      #pragma unroll
      for (int q=0;q<8;q++) atomicAdd(&fwacc[r*Nq + c0 + q], fa[r][q]);
    __syncthreads();
    #pragma unroll
    for (int i=0;i<4;i++){
      int id = i*512 + tid; int r = id>>9, k = id&511;
      p.fwpart[(((size_t)(b*8+g))*Rq + r)*Nq + k] = fwacc[id];
    }
  } else {
    int b = bid - 128;
    const float* xib = p.xi + (size_t)b*XIPq;
    keyv[tid] = xib[tid];                 // raw read keys 0..511
    if (tid < Wq){ wv[tid] = xib[640+tid]; er[tid] = sigf(xib[768+tid]); }
    __syncthreads();
    float kn4[4], rstr[4];
    #pragma unroll
    for (int r=0;r<Rq;r++){
      float kk = (tid<Wq)? keyv[r*Wq+tid]*keyv[r*Wq+tid] : 0.f;
      kn4[r] = sqrtf(blk_sum(kk, s8));
      rstr[r] = oneplusf(xib[900+r]);
    }
    int n = tid;
    float keep = 1.f - (float)p.rst[b*Tq + t];
    float wwn = p.ww[b*Nq+n];
    float4* mrow = (float4*)(p.memv + ((size_t)b*Nq+n)*Mq);
    float* mT = p.memvT + (size_t)b*Nq*Mq;
    const float4* er4 = (const float4*)er;
    const float4* wv4 = (const float4*)wv;
    const float4* k40 = (const float4*)(keyv);
    const float4* k41 = (const float4*)(keyv+128);
    const float4* k42 = (const float4*)(keyv+256);
    const float4* k43 = (const float4*)(keyv+384);
    float s = 0.f, d0=0.f, d1=0.f, d2=0.f, d3=0.f;
    #pragma unroll 4
    for (int c=0;c<32;c++){
      float4 mv = mrow[c], e4 = er4[c], w4 = wv4[c];
      mv.x = mv.x*keep*(1.f - wwn*e4.x) + wwn*w4.x;
      mv.y = mv.y*keep*(1.f - wwn*e4.y) + wwn*w4.y;
      mv.z = mv.z*keep*(1.f - wwn*e4.z) + wwn*w4.z;
      mv.w = mv.w*keep*(1.f - wwn*e4.w) + wwn*w4.w;
      s += dot4(mv,mv);
      d0 += dot4(k40[c], mv); d1 += dot4(k41[c], mv);
      d2 += dot4(k42[c], mv); d3 += dot4(k43[c], mv);
      mrow[c] = mv;
      mT[(4*c+0)*Nq + n] = mv.x; mT[(4*c+1)*Nq + n] = mv.y;
      mT[(4*c+2)*Nq + n] = mv.z; mT[(4*c+3)*Nq + n] = mv.w;
    }
    float mn = sqrtf(s);
    p.norms[b*Nq+n] = mn;
    float dd[4] = {d0,d1,d2,d3};
    #pragma unroll
    for (int r=0;r<Rq;r++){
      float v = rstr[r] * (dd[r] / (kn4[r]*mn + 1e-6f));
      float mx = blk_max(v, s8);
      float e = expf(v - mx);
      float se = blk_sum(e, s8);
      p.rca[((size_t)(b*Rq+r))*Nq + n] = e/se;
    }
  }
}

extern "C" void kernel_launch(void* const* d_in, const int* in_sizes, int n_in,
                              void* d_out, int out_size, void* d_ws, size_t ws_size,
                              hipStream_t stream){
  (void)in_sizes; (void)n_in; (void)out_size; (void)ws_size;
  P p;
  p.X    = (const float*)d_in[0];
  p.hs0  = (const float*)d_in[1];
  p.mem0 = (const float*)d_in[2];
  p.rst  = (const int*)d_in[3];
  p.Wb   = (const float*)d_in[4];  p.bb   = (const float*)d_in[5];
  p.Wff1 = (const float*)d_in[6];  p.bff1 = (const float*)d_in[7];
  p.Wff2 = (const float*)d_in[8];  p.bff2 = (const float*)d_in[9];
  p.Wta  = (const float*)d_in[10]; p.bta  = (const float*)d_in[11];
  p.Wtb  = (const float*)d_in[12]; p.btb  = (const float*)d_in[13];
  p.Wv   = (const float*)d_in[14]; p.bv   = (const float*)d_in[15];
  p.Wr   = (const float*)d_in[16]; p.br   = (const float*)d_in[17];
  p.Wxi  = (const float*)d_in[18]; p.bxi  = (const float*)d_in[19];
  p.out = (float*)d_out;
  float* ws = (float*)d_ws;
  size_t o = 0;
  p.memv   = ws + o; o += (size_t)Bq*Nq*Mq;       // 1,048,576
  p.memvT  = ws + o; o += (size_t)Bq*Nq*Mq;       // 1,048,576
  p.link   = ws + o; o += (size_t)Bq*Nq*Nq;       // 4,194,304
  p.fwpart = ws + o; o += (size_t)Bq*8*Rq*Nq;     //   262,144
  p.bw     = ws + o; o += (size_t)Bq*Rq*Nq;
  p.rw     = ws + o; o += (size_t)Bq*Rq*Nq;
  p.rca    = ws + o; o += (size_t)Bq*Rq*Nq;
  p.hs     = ws + o; o += (size_t)Bq*Wq;
  p.reads  = ws + o; o += (size_t)Bq*Rq*Wq;
  p.z      = ws + o; o += (size_t)Bq*Wq;
  p.ww     = ws + o; o += (size_t)Bq*Nq;
  p.usage  = ws + o; o += (size_t)Bq*Nq;
  p.prec0  = ws + o; o += (size_t)Bq*Nq;
  p.prec1  = ws + o; o += (size_t)Bq*Nq;
  p.norms  = ws + o; o += (size_t)Bq*Nq;
  p.xi     = ws + o; o += (size_t)Bq*XIPq;
  p.WbT    = ws + o; o += (size_t)DINq*Wq;
  p.Wff1T  = ws + o; o += (size_t)Wq*Wq;
  p.Wff2T  = ws + o; o += (size_t)Wq*Wq;
  p.WtaT   = ws + o; o += (size_t)Wq*Wq;
  p.WtbT   = ws + o; o += (size_t)Wq*Wq;
  p.WvT    = ws + o; o += (size_t)Wq*Wq;
  p.WrT    = ws + o; o += (size_t)Rq*Wq*Wq;
  p.WxiT   = ws + o; o += (size_t)919*Wq;

  hipLaunchKernelGGL(k_init, dim3(320), dim3(256), 0, stream, p);
  for (int t=0; t<Tq; t++){
    if (t > 0) hipLaunchKernelGGL(k1, dim3(64), dim3(512), 0, stream, p, t);
    hipLaunchKernelGGL(k2,  dim3(256), dim3(256), 0, stream, p, t);
    hipLaunchKernelGGL(k3,  dim3(128), dim3(256), 0, stream, p, t);
    hipLaunchKernelGGL(k45, dim3(112), dim3(512), 0, stream, p, t);
    hipLaunchKernelGGL(k6,  dim3(144), dim3(512), 0, stream, p, t);
  }
  hipLaunchKernelGGL(k1, dim3(64),  dim3(512), 0, stream, p, Tq);
  hipLaunchKernelGGL(k2, dim3(256), dim3(256), 0, stream, p, Tq);
}